// Round 10
// baseline (574.127 us; speedup 1.0000x reference)
//
#include <hip/hip_runtime.h>
#include <hip/hip_bf16.h>

typedef __attribute__((ext_vector_type(8))) short bf16x8;   // 8 bf16 = 4 VGPRs
typedef __attribute__((ext_vector_type(4))) float f32x4;    // 4 f32 acc

static __device__ __forceinline__ float bf2f(__hip_bfloat16 v) { return __bfloat162float(v); }

static __device__ __forceinline__ float bs2f(short s) {
    unsigned u = ((unsigned)(unsigned short)s) << 16;
    float f; __builtin_memcpy(&f, &u, 4); return f;
}
static __device__ __forceinline__ short f2bs(float v) {
    __hip_bfloat16 b = __float2bfloat16(v);
    short s; __builtin_memcpy(&s, &b, 2); return s;
}
// read element i of a float array that is either f32 or bf16
static __device__ __forceinline__ float loadf(const void* p, int i, bool f32) {
    if (f32) return ((const float*)p)[i];
    return bf2f(((const __hip_bfloat16*)p)[i]);
}

// ------------------------------------------------- runtime dtype detection
// flags[0] = 1 if edge_index is int64; flags[1] = 1 if float inputs are f32
__global__ __launch_bounds__(256) void detect_kernel(const unsigned* __restrict__ ew,
        const unsigned short* __restrict__ xw, int* __restrict__ flags) {
    __shared__ int s_odd, s_f32;
    int t = threadIdx.x;
    if (t == 0) { s_odd = 0; s_f32 = 0; }
    __syncthreads();
    unsigned acc = 0;
    for (int i = t; i < 2048; i += 256) acc |= ew[2 * i + 1];
    if (acc) atomicOr(&s_odd, 1);
    int f32ev = 0;
    for (int i = t; i < 4096; i += 256) {
        unsigned e = (xw[i] >> 7) & 0xFF;          // bf16 exponent field
        if (e >= 0xC0) f32ev = 1;                  // impossible for real bf16 data
    }
    if (f32ev) atomicOr(&s_f32, 1);
    __syncthreads();
    if (t == 0) { flags[0] = s_odd ? 0 : 1; flags[1] = s_f32; }
}

// ---------------------------------------------------------------- CSR build v2
// Two-level binned counting sort (R8): fine scatter confines each block's
// writes to its own bin's span -> ~1x HBM writeback (R7 flat scatter was 16x).

static __device__ __forceinline__ int dec_src(const unsigned* ew, int E, bool i64, int e) {
    return i64 ? (int)ew[2 * (size_t)e] : (int)ew[e];
}
static __device__ __forceinline__ int dec_dst(const unsigned* ew, int E, bool i64, int e) {
    return i64 ? (int)ew[2 * (size_t)E + 2 * (size_t)e] : (int)ew[(size_t)E + e];
}

__global__ __launch_bounds__(256) void coarse_count(const unsigned* __restrict__ ew, int E,
        const int* __restrict__ flags, int* __restrict__ ccnt) {
    __shared__ int h[512];
    int tid = threadIdx.x;
    for (int i = tid; i < 512; i += 256) h[i] = 0;
    __syncthreads();
    bool i64 = flags[0] != 0;
    int base = blockIdx.x * 8192;
    int lim = min(base + 8192, E);
    for (int e = base + tid; e < lim; e += 256)
        atomicAdd(&h[dec_dst(ew, E, i64, e) >> 8], 1);
    __syncthreads();
    for (int i = tid; i < 512; i += 256) if (h[i]) atomicAdd(&ccnt[i], h[i]);
}

__global__ __launch_bounds__(256) void coarse_scan(const int* __restrict__ ccnt,
        int* __restrict__ cbase, int* __restrict__ ccur, int NBINS) {
    __shared__ int part[256];
    int t = threadIdx.x;
    int v0 = (2 * t     < NBINS) ? ccnt[2 * t]     : 0;
    int v1 = (2 * t + 1 < NBINS) ? ccnt[2 * t + 1] : 0;
    int sum = v0 + v1;
    part[t] = sum;
    __syncthreads();
    for (int off = 1; off < 256; off <<= 1) {
        int u = (t >= off) ? part[t - off] : 0;
        __syncthreads();
        part[t] += u;
        __syncthreads();
    }
    int run = part[t] - sum;
    if (2 * t < NBINS)     { cbase[2 * t] = run;     ccur[2 * t] = run; }
    run += v0;
    if (2 * t + 1 < NBINS) { cbase[2 * t + 1] = run; ccur[2 * t + 1] = run; }
    if (t == 255) cbase[NBINS] = part[255];
}

__global__ __launch_bounds__(256) void coarse_scatter(const unsigned* __restrict__ ew, int E,
        const int* __restrict__ flags, int* __restrict__ ccur,
        uint2* __restrict__ pairs, int NBINS) {
    __shared__ int hist[512];
    __shared__ int hscan[513];
    __shared__ int fbase[512];
    __shared__ int part[256];
    __shared__ uint2 stage[2048];
    int tid = threadIdx.x;
    bool i64 = flags[0] != 0;
    int base = blockIdx.x * 2048;
    int cnt = min(2048, E - base);
    for (int i = tid; i < 512; i += 256) hist[i] = 0;
    __syncthreads();
    int myb[8], myo[8], mys[8], myd[8];
    #pragma unroll
    for (int j = 0; j < 8; ++j) {
        int e = base + j * 256 + tid;
        myb[j] = -1;
        if (e < E) {
            mys[j] = dec_src(ew, E, i64, e);
            int d = dec_dst(ew, E, i64, e);
            myd[j] = d & 255;
            myb[j] = d >> 8;
            myo[j] = atomicAdd(&hist[myb[j]], 1);
        }
    }
    __syncthreads();
    {
        int v0 = hist[2 * tid], v1 = hist[2 * tid + 1];
        int sum = v0 + v1;
        part[tid] = sum;
        __syncthreads();
        for (int off = 1; off < 256; off <<= 1) {
            int u = (tid >= off) ? part[tid - off] : 0;
            __syncthreads();
            part[tid] += u;
            __syncthreads();
        }
        int run = part[tid] - sum;
        hscan[2 * tid] = run;
        hscan[2 * tid + 1] = run + v0;
        if (tid == 255) hscan[512] = part[255];
    }
    __syncthreads();
    #pragma unroll
    for (int j = 0; j < 8; ++j)
        if (myb[j] >= 0) {
            uint2 p; p.x = (unsigned)mys[j]; p.y = (unsigned)myd[j];
            stage[hscan[myb[j]] + myo[j]] = p;
        }
    for (int i = tid; i < NBINS; i += 256) {
        int c = hist[i];
        if (c) fbase[i] = atomicAdd(&ccur[i], c);
    }
    __syncthreads();
    for (int i = tid; i < cnt; i += 256) {
        int lo = 0, hi = NBINS;
        while (hi - lo > 1) {
            int mid = (lo + hi) >> 1;
            if (hscan[mid] <= i) lo = mid; else hi = mid;
        }
        pairs[(size_t)fbase[lo] + (i - hscan[lo])] = stage[i];
    }
}

__global__ __launch_bounds__(256) void bin_degree(const uint2* __restrict__ pairs,
        const int* __restrict__ cbase, int* __restrict__ deg, int N) {
    __shared__ int dl[256];
    int tid = threadIdx.x, b = blockIdx.x;
    dl[tid] = 0;
    __syncthreads();
    int s = cbase[b], e = cbase[b + 1];
    for (int i = s + tid; i < e; i += 256) atomicAdd(&dl[pairs[i].y], 1);
    __syncthreads();
    int node = (b << 8) + tid;
    if (node < N) deg[node] = dl[tid];
}

__global__ __launch_bounds__(256) void bin_scatter(const uint2* __restrict__ pairs,
        const int* __restrict__ cbase, const int* __restrict__ rowptr,
        int* __restrict__ ebuf, int N) {
    __shared__ int cur[256];
    int tid = threadIdx.x, b = blockIdx.x;
    int node = (b << 8) + tid;
    cur[tid] = (node < N) ? rowptr[node] : 0;
    __syncthreads();
    int s = cbase[b], e = cbase[b + 1];
    for (int i = s + tid; i < e; i += 256) {
        uint2 p = pairs[i];
        int pos = atomicAdd(&cur[p.y], 1);
        ebuf[pos] = (int)p.x;
    }
}

// ---- 3-phase multi-block exclusive scan over deg ----
__global__ __launch_bounds__(256) void scan_phaseA(const int* __restrict__ deg,
        int* __restrict__ blocksum, int N) {
    __shared__ int red[256];
    int i0 = blockIdx.x * 512 + threadIdx.x * 2;
    int s = 0;
    if (i0 < N)     s += deg[i0];
    if (i0 + 1 < N) s += deg[i0 + 1];
    red[threadIdx.x] = s;
    __syncthreads();
    for (int off = 128; off; off >>= 1) {
        if (threadIdx.x < off) red[threadIdx.x] += red[threadIdx.x + off];
        __syncthreads();
    }
    if (threadIdx.x == 0) blocksum[blockIdx.x] = red[0];
}

__global__ __launch_bounds__(256) void scan_phaseB(int* __restrict__ blocksum, int NB,
        int* __restrict__ rowptr, int N) {
    __shared__ int part[256];
    int t = threadIdx.x;
    int v[4]; int sum = 0;
    #pragma unroll
    for (int j = 0; j < 4; ++j) {
        int i = 4 * t + j;
        v[j] = (i < NB) ? blocksum[i] : 0;
        sum += v[j];
    }
    part[t] = sum;
    __syncthreads();
    for (int off = 1; off < 256; off <<= 1) {
        int u = (t >= off) ? part[t - off] : 0;
        __syncthreads();
        part[t] += u;
        __syncthreads();
    }
    int run = part[t] - sum;
    #pragma unroll
    for (int j = 0; j < 4; ++j) {
        int i = 4 * t + j;
        if (i < NB) blocksum[i] = run;
        run += v[j];
    }
    if (t == 255) rowptr[N] = part[255];
}

__global__ __launch_bounds__(256) void scan_phaseC(const int* __restrict__ deg,
        const int* __restrict__ blockoff, int* __restrict__ rowptr, int N) {
    __shared__ int part[256];
    int t = threadIdx.x;
    int i0 = blockIdx.x * 512 + 2 * t;
    int d0 = (i0 < N)     ? deg[i0]     : 0;
    int d1 = (i0 + 1 < N) ? deg[i0 + 1] : 0;
    int sum = d0 + d1;
    part[t] = sum;
    __syncthreads();
    for (int off = 1; off < 256; off <<= 1) {
        int u = (t >= off) ? part[t - off] : 0;
        __syncthreads();
        part[t] += u;
        __syncthreads();
    }
    int run = blockoff[blockIdx.x] + part[t] - sum;
    if (i0 < N)     rowptr[i0] = run;
    run += d0;
    if (i0 + 1 < N) rowptr[i0 + 1] = run;
}

// ------------------------------------------------------- weight pre-transpose
__global__ void transpose_kernel(const void* __restrict__ W,
        __hip_bfloat16* __restrict__ Wt, int rows, int cols, int ldt,
        const int* __restrict__ flags) {
    int idx = blockIdx.x * blockDim.x + threadIdx.x;
    if (idx < rows * cols) {
        int fi = idx / cols, fo = idx % cols;
        Wt[fo * ldt + fi] = __float2bfloat16(loadf(W, idx, flags[1] != 0));
    }
}

// --------------------------------------------------------------- MFMA GEMM v6
// Block = 128 nodes as 4 waves x TWO 16-node stripes each (256 threads).
// One ds_read of a W-fragment now feeds TWO MFMAs (stripes A and B):
// halves LDS-read traffic (R9's per-CU LDS pipe serialization, ~12us) and
// gives 8 independent MFMA chains per barrier instead of 4. xf regs ~64
// VGPRs -> total ~115, still 4 waves/SIMD. Swizzled W layout as R9.
template<int KSTEPS>
__global__ __launch_bounds__(256) void gemm_v6(
        const void* __restrict__ X0, const void* __restrict__ X1, int K0, int xflag,
        const __hip_bfloat16* __restrict__ Wt, const void* __restrict__ bias,
        void* __restrict__ outp, int ldo, int out_f32, int M, int Ncols,
        const int* __restrict__ flags) {
    constexpr int K = KSTEPS * 32;
    constexpr int CH = K / 8;              // 16B chunks per W row
    constexpr int SITERS = (64 * CH) / 256;
    __shared__ short Wf[4 * KSTEPS * 64 * 8];   // 32KB @ K=256
    bool pf = flags[1] != 0;
    bool xf32 = (xflag != 0) && pf;
    int tid = threadIdx.x;
    int wave = tid >> 6, lane = tid & 63;
    int quad = lane >> 4, r = lane & 15;
    int nodeA = blockIdx.x * 128 + wave * 32 + r;
    int nodeB = nodeA + 16;
    int nA = min(nodeA, M - 1);
    int nB = min(nodeB, M - 1);

    bf16x8 xfA[KSTEPS], xfB[KSTEPS];
    if (xf32) {
        #pragma unroll
        for (int ks = 0; ks < KSTEPS; ++ks) {
            int k = ks * 32 + quad * 8;
            const float* pA = (k < K0)
                ? ((const float*)X0 + (size_t)nA * K0 + k)
                : ((const float*)X1 + (size_t)nA * (K - K0) + (k - K0));
            const float* pB = (k < K0)
                ? ((const float*)X0 + (size_t)nB * K0 + k)
                : ((const float*)X1 + (size_t)nB * (K - K0) + (k - K0));
            float4 a0 = *(const float4*)pA;
            float4 a1 = *(const float4*)(pA + 4);
            float4 b0 = *(const float4*)pB;
            float4 b1 = *(const float4*)(pB + 4);
            bf16x8 ta, tb;
            ta[0] = f2bs(a0.x); ta[1] = f2bs(a0.y); ta[2] = f2bs(a0.z); ta[3] = f2bs(a0.w);
            ta[4] = f2bs(a1.x); ta[5] = f2bs(a1.y); ta[6] = f2bs(a1.z); ta[7] = f2bs(a1.w);
            tb[0] = f2bs(b0.x); tb[1] = f2bs(b0.y); tb[2] = f2bs(b0.z); tb[3] = f2bs(b0.w);
            tb[4] = f2bs(b1.x); tb[5] = f2bs(b1.y); tb[6] = f2bs(b1.z); tb[7] = f2bs(b1.w);
            xfA[ks] = ta;
            xfB[ks] = tb;
        }
    } else {
        #pragma unroll
        for (int ks = 0; ks < KSTEPS; ++ks) {
            int k = ks * 32 + quad * 8;
            const __hip_bfloat16* pA = (k < K0)
                ? ((const __hip_bfloat16*)X0 + (size_t)nA * K0 + k)
                : ((const __hip_bfloat16*)X1 + (size_t)nA * (K - K0) + (k - K0));
            const __hip_bfloat16* pB = (k < K0)
                ? ((const __hip_bfloat16*)X0 + (size_t)nB * K0 + k)
                : ((const __hip_bfloat16*)X1 + (size_t)nB * (K - K0) + (k - K0));
            xfA[ks] = *(const bf16x8*)pA;
            xfB[ks] = *(const bf16x8*)pB;
        }
    }

    int nphases = Ncols >> 6;              // 64 cols per phase
    for (int p = 0; p < nphases; ++p) {
        if (p) __syncthreads();
        // ---- stage 64 W rows into swizzled fragment layout ----
        #pragma unroll
        for (int i = 0; i < SITERS; ++i) {
            int idx = i * 256 + tid;
            int row_l = idx / CH, c = idx % CH;     // consecutive tid -> consecutive c (coalesced)
            uint4 v = *(const uint4*)((const short*)Wt + (size_t)(p * 64 + row_l) * K + c * 8);
            int ftl = row_l >> 4, rr = row_l & 15;
            int ks = c >> 2, q = c & 3;
            int chunk = ((q * 16 + rr) ^ ks);       // XOR swizzle
            *(uint4*)(Wf + (size_t)(((ftl * KSTEPS + ks) * 64) + chunk) * 8) = v;
        }
        __syncthreads();
        // ---- compute: 4 ftiles x 2 stripes = 8 independent MFMA chains ----
        #pragma unroll
        for (int ftl = 0; ftl < 4; ++ftl) {
            f32x4 accA = {0.f, 0.f, 0.f, 0.f};
            f32x4 accB = {0.f, 0.f, 0.f, 0.f};
            #pragma unroll
            for (int ks = 0; ks < KSTEPS; ++ks) {
                bf16x8 wf = *(const bf16x8*)(Wf + (size_t)((ftl * KSTEPS + ks) * 64 + (lane ^ ks)) * 8);
                accA = __builtin_amdgcn_mfma_f32_16x16x32_bf16(wf, xfA[ks], accA, 0, 0, 0);
                accB = __builtin_amdgcn_mfma_f32_16x16x32_bf16(wf, xfB[ks], accB, 0, 0, 0);
            }
            int fo = p * 64 + ftl * 16 + quad * 4;
            float b0 = 0.f, b1 = 0.f, b2 = 0.f, b3 = 0.f;
            if (bias) {
                b0 = loadf(bias, fo + 0, pf); b1 = loadf(bias, fo + 1, pf);
                b2 = loadf(bias, fo + 2, pf); b3 = loadf(bias, fo + 3, pf);
            }
            if (out_f32) {
                if (nodeA < M) {
                    float4 res;
                    res.x = accA[0] + b0; res.y = accA[1] + b1;
                    res.z = accA[2] + b2; res.w = accA[3] + b3;
                    *(float4*)((float*)outp + (size_t)nodeA * ldo + fo) = res;
                }
                if (nodeB < M) {
                    float4 res;
                    res.x = accB[0] + b0; res.y = accB[1] + b1;
                    res.z = accB[2] + b2; res.w = accB[3] + b3;
                    *(float4*)((float*)outp + (size_t)nodeB * ldo + fo) = res;
                }
            } else {
                if (nodeA < M) {
                    short4 res;
                    res.x = f2bs(accA[0] + b0); res.y = f2bs(accA[1] + b1);
                    res.z = f2bs(accA[2] + b2); res.w = f2bs(accA[3] + b3);
                    *(short4*)((short*)outp + (size_t)nodeA * ldo + fo) = res;
                }
                if (nodeB < M) {
                    short4 res;
                    res.x = f2bs(accB[0] + b0); res.y = f2bs(accB[1] + b1);
                    res.z = f2bs(accB[2] + b2); res.w = f2bs(accB[3] + b3);
                    *(short4*)((short*)outp + (size_t)nodeB * ldo + fo) = res;
                }
            }
        }
    }
}

// --------------------------------------- fused mean-agg + bias + lin_r + LN + ReLU
__global__ __launch_bounds__(256) void agg_ln_relu(
        const __hip_bfloat16* __restrict__ yz, const int* __restrict__ rowptr,
        const int* __restrict__ ebuf,
        const void* __restrict__ bn, const void* __restrict__ g,
        const void* __restrict__ be, __hip_bfloat16* __restrict__ hout, int N,
        const int* __restrict__ flags) {
    int node = (blockIdx.x * blockDim.x + threadIdx.x) >> 6;
    if (node >= N) return;
    node = __builtin_amdgcn_readfirstlane(node);
    bool pf = flags[1] != 0;
    int lane = threadIdx.x & 63;
    int f = lane * 2;
    const short* yzs = (const short*)yz;
    int start = rowptr[node], end = rowptr[node + 1];
    float a0 = 0.f, a1 = 0.f;
    int i = start;
    for (; i + 8 <= end; i += 8) {
        int n0 = ebuf[i + 0], n1 = ebuf[i + 1], n2 = ebuf[i + 2], n3 = ebuf[i + 3];
        int n4 = ebuf[i + 4], n5 = ebuf[i + 5], n6 = ebuf[i + 6], n7 = ebuf[i + 7];
        short2 t0 = *(const short2*)(yzs + (size_t)n0 * 256 + f);
        short2 t1 = *(const short2*)(yzs + (size_t)n1 * 256 + f);
        short2 t2 = *(const short2*)(yzs + (size_t)n2 * 256 + f);
        short2 t3 = *(const short2*)(yzs + (size_t)n3 * 256 + f);
        short2 t4 = *(const short2*)(yzs + (size_t)n4 * 256 + f);
        short2 t5 = *(const short2*)(yzs + (size_t)n5 * 256 + f);
        short2 t6 = *(const short2*)(yzs + (size_t)n6 * 256 + f);
        short2 t7 = *(const short2*)(yzs + (size_t)n7 * 256 + f);
        a0 += bs2f(t0.x) + bs2f(t1.x) + bs2f(t2.x) + bs2f(t3.x)
            + bs2f(t4.x) + bs2f(t5.x) + bs2f(t6.x) + bs2f(t7.x);
        a1 += bs2f(t0.y) + bs2f(t1.y) + bs2f(t2.y) + bs2f(t3.y)
            + bs2f(t4.y) + bs2f(t5.y) + bs2f(t6.y) + bs2f(t7.y);
    }
    for (; i + 2 <= end; i += 2) {
        int n0 = ebuf[i + 0], n1 = ebuf[i + 1];
        short2 t0 = *(const short2*)(yzs + (size_t)n0 * 256 + f);
        short2 t1 = *(const short2*)(yzs + (size_t)n1 * 256 + f);
        a0 += bs2f(t0.x) + bs2f(t1.x);
        a1 += bs2f(t0.y) + bs2f(t1.y);
    }
    if (i < end) {
        int n0 = ebuf[i];
        short2 t0 = *(const short2*)(yzs + (size_t)n0 * 256 + f);
        a0 += bs2f(t0.x);
        a1 += bs2f(t0.y);
    }
    float inv = 1.f / fmaxf((float)(end - start), 1.f);
    short2 zt = *(const short2*)(yzs + (size_t)node * 256 + 128 + f);
    float v0 = a0 * inv + loadf(bn, f, pf)     + bs2f(zt.x);
    float v1 = a1 * inv + loadf(bn, f + 1, pf) + bs2f(zt.y);
    float s = v0 + v1;
    #pragma unroll
    for (int off = 32; off > 0; off >>= 1) s += __shfl_xor(s, off, 64);
    float mu = s * (1.f / 128.f);
    float d0 = v0 - mu, d1 = v1 - mu;
    float q = d0 * d0 + d1 * d1;
    #pragma unroll
    for (int off = 32; off > 0; off >>= 1) q += __shfl_xor(q, off, 64);
    float rstd = rsqrtf(q * (1.f / 128.f) + 1e-5f);
    float o0 = fmaxf(d0 * rstd * loadf(g, f, pf)     + loadf(be, f, pf),     0.f);
    float o1 = fmaxf(d1 * rstd * loadf(g, f + 1, pf) + loadf(be, f + 1, pf), 0.f);
    short* hp = (short*)hout + (size_t)node * 128 + f;
    hp[0] = f2bs(o0);
    hp[1] = f2bs(o1);
}

// ------------------------------------------------------------- MLP head
__global__ __launch_bounds__(256) void head_kernel(
        const float* __restrict__ feats, const void* __restrict__ Wh1,
        const void* __restrict__ bh1, const void* __restrict__ Wh2,
        const void* __restrict__ bh2, void* __restrict__ outp, int N,
        const int* __restrict__ flags) {
    __shared__ float sfe[8 * 128];
    __shared__ float shid[8 * 32];
    bool pf = flags[1] != 0;
    int nb = blockIdx.x * 8;
    int tid = threadIdx.x;
    {
        int i = tid * 4;
        int gnode = nb + (i >> 7);
        float4 v = make_float4(0.f, 0.f, 0.f, 0.f);
        if (gnode < N) v = *(const float4*)(feats + (size_t)gnode * 128 + (i & 127));
        *(float4*)(sfe + i) = v;
    }
    __syncthreads();
    {
        int nloc = tid >> 5, col = tid & 31;
        float acc = loadf(bh1, col, pf);
        const float* fr = sfe + nloc * 128;
        #pragma unroll 8
        for (int k = 0; k < 128; ++k) acc += fr[k] * loadf(Wh1, k * 32 + col, pf);
        shid[nloc * 32 + col] = fmaxf(acc, 0.f);
    }
    __syncthreads();
    if (tid < 128) {
        int nloc = tid >> 4, col = tid & 15;
        int gnode = nb + nloc;
        if (gnode < N) {
            float acc = loadf(bh2, col, pf);
            const float* hr = shid + nloc * 32;
            #pragma unroll
            for (int k = 0; k < 32; ++k) acc += hr[k] * loadf(Wh2, k * 16 + col, pf);
            if (pf) ((float*)outp)[(size_t)gnode * 16 + col] = acc;
            else    ((__hip_bfloat16*)outp)[(size_t)gnode * 16 + col] = __float2bfloat16(acc);
        }
    }
}

// ---------------------------------------------------------------- launcher
extern "C" void kernel_launch(void* const* d_in, const int* in_sizes, int n_in,
                              void* d_out, int out_size, void* d_ws, size_t ws_size,
                              hipStream_t stream) {
    const void* x    = d_in[0];
    const unsigned* ei = (const unsigned*)d_in[1];
    const void* Wnl0 = d_in[2];
    const void* bnl0 = d_in[3];
    const void* Wr0  = d_in[4];
    const void* Wnl1 = d_in[5];
    const void* bnl1 = d_in[6];
    const void* Wr1  = d_in[7];
    const void* g0   = d_in[8];
    const void* be0  = d_in[9];
    const void* g1   = d_in[10];
    const void* be1  = d_in[11];
    const void* Wjk  = d_in[12];
    const void* bjk  = d_in[13];
    const void* Wh1  = d_in[14];
    const void* bh1  = d_in[15];
    const void* Wh2  = d_in[16];
    const void* bh2  = d_in[17];

    const int N = in_sizes[0] / 256;
    const int E = in_sizes[1] / 2;
    const int NBINS = (N + 255) >> 8;

    char* ws = (char*)d_ws;
    size_t off = 0;
    auto alloc = [&](size_t bytes) -> void* {
        void* p = ws + off;
        off = (off + bytes + 255) & ~(size_t)255;
        return p;
    };
    int* flags  = (int*)alloc(256);
    int* rowptr = (int*)alloc((size_t)(N + 1) * 4);
    int* deg    = (int*)alloc((size_t)N * 4);
    int* ebuf   = (int*)alloc((size_t)E * 4);
    int* blocksum = (int*)alloc(1024 * 4);
    int* ccnt   = (int*)alloc(512 * 4);
    int* cbase  = (int*)alloc(513 * 4);
    int* ccur   = (int*)alloc(512 * 4);
    uint2* pairs = (uint2*)alloc((size_t)E * 8);
    __hip_bfloat16* Wt0  = (__hip_bfloat16*)alloc(256 * 256 * 2);
    __hip_bfloat16* Wt1  = (__hip_bfloat16*)alloc(256 * 128 * 2);
    __hip_bfloat16* Wtjk = (__hip_bfloat16*)alloc(128 * 256 * 2);
    __hip_bfloat16* yz = (__hip_bfloat16*)alloc((size_t)N * 256 * 2);
    __hip_bfloat16* h0 = (__hip_bfloat16*)alloc((size_t)N * 128 * 2);
    __hip_bfloat16* h1 = (__hip_bfloat16*)alloc((size_t)N * 128 * 2);
    float* feats = (float*)yz;   // yz dead after second agg; same byte size

    // dtype detection
    detect_kernel<<<1, 256, 0, stream>>>(ei, (const unsigned short*)x, flags);

    // CSR build v2 (two-level binned counting sort)
    (void)hipMemsetAsync(ccnt, 0, 512 * 4, stream);
    coarse_count<<<(E + 8191) / 8192, 256, 0, stream>>>(ei, E, flags, ccnt);
    coarse_scan<<<1, 256, 0, stream>>>(ccnt, cbase, ccur, NBINS);
    coarse_scatter<<<(E + 2047) / 2048, 256, 0, stream>>>(ei, E, flags, ccur, pairs, NBINS);
    bin_degree<<<NBINS, 256, 0, stream>>>(pairs, cbase, deg, N);
    int NB = (N + 511) / 512;
    scan_phaseA<<<NB, 256, 0, stream>>>(deg, blocksum, N);
    scan_phaseB<<<1, 256, 0, stream>>>(blocksum, NB, rowptr, N);
    scan_phaseC<<<NB, 256, 0, stream>>>(deg, blocksum, rowptr, N);
    bin_scatter<<<NBINS, 256, 0, stream>>>(pairs, cbase, rowptr, ebuf, N);

    // Weight transposes
    transpose_kernel<<<(256 * 128 + 255) / 256, 256, 0, stream>>>(Wnl0, Wt0, 256, 128, 256, flags);
    transpose_kernel<<<(256 * 128 + 255) / 256, 256, 0, stream>>>(Wr0,  Wt0 + 128 * 256, 256, 128, 256, flags);
    transpose_kernel<<<(128 * 128 + 255) / 256, 256, 0, stream>>>(Wnl1, Wt1, 128, 128, 128, flags);
    transpose_kernel<<<(128 * 128 + 255) / 256, 256, 0, stream>>>(Wr1,  Wt1 + 128 * 128, 128, 128, 128, flags);
    transpose_kernel<<<(256 * 128 + 255) / 256, 256, 0, stream>>>(Wjk,  Wtjk, 256, 128, 256, flags);

    int gblocks = (N + 127) / 128;    // 128 nodes per block (4 waves x 2 stripes)
    int ablocks = (int)(((size_t)N * 64 + 255) / 256);

    // layer 0: project (y0 = x@Wnl0, z0 = x@Wr0) -> agg+LN+ReLU -> h0
    gemm_v6<8><<<gblocks, 256, 0, stream>>>(x, x, 256, 1, Wt0, nullptr, yz, 256, 0, N, 256, flags);
    agg_ln_relu<<<ablocks, 256, 0, stream>>>(yz, rowptr, ebuf, bnl0, g0, be0, h0, N, flags);

    // layer 1 (K=128)
    gemm_v6<4><<<gblocks, 256, 0, stream>>>(h0, h0, 128, 0, Wt1, nullptr, yz, 256, 0, N, 256, flags);
    agg_ln_relu<<<ablocks, 256, 0, stream>>>(yz, rowptr, ebuf, bnl1, g1, be1, h1, N, flags);

    // JK: feats = [h0|h1] @ Wjk + bjk   (K split 128/128), f32 output
    gemm_v6<8><<<gblocks, 256, 0, stream>>>(h0, h1, 128, 0, Wtjk, bjk, feats, 128, 1, N, 128, flags);

    // MLP head
    head_kernel<<<(N + 7) / 8, 256, 0, stream>>>(feats, Wh1, bh1, Wh2, bh2, d_out, N, flags);
}

// Round 11
// 530.629 us; speedup vs baseline: 1.0820x; 1.0820x over previous
//
#include <hip/hip_runtime.h>
#include <hip/hip_bf16.h>

typedef __attribute__((ext_vector_type(8))) short bf16x8;   // 8 bf16 = 4 VGPRs
typedef __attribute__((ext_vector_type(4))) float f32x4;    // 4 f32 acc

static __device__ __forceinline__ float bf2f(__hip_bfloat16 v) { return __bfloat162float(v); }

static __device__ __forceinline__ float bs2f(short s) {
    unsigned u = ((unsigned)(unsigned short)s) << 16;
    float f; __builtin_memcpy(&f, &u, 4); return f;
}
static __device__ __forceinline__ short f2bs(float v) {
    __hip_bfloat16 b = __float2bfloat16(v);
    short s; __builtin_memcpy(&s, &b, 2); return s;
}
// read element i of a float array that is either f32 or bf16
static __device__ __forceinline__ float loadf(const void* p, int i, bool f32) {
    if (f32) return ((const float*)p)[i];
    return bf2f(((const __hip_bfloat16*)p)[i]);
}

// ------------------------------------------------- runtime dtype detection
// flags[0] = 1 if edge_index is int64; flags[1] = 1 if float inputs are f32
__global__ __launch_bounds__(256) void detect_kernel(const unsigned* __restrict__ ew,
        const unsigned short* __restrict__ xw, int* __restrict__ flags) {
    __shared__ int s_odd, s_f32;
    int t = threadIdx.x;
    if (t == 0) { s_odd = 0; s_f32 = 0; }
    __syncthreads();
    unsigned acc = 0;
    for (int i = t; i < 2048; i += 256) acc |= ew[2 * i + 1];
    if (acc) atomicOr(&s_odd, 1);
    int f32ev = 0;
    for (int i = t; i < 4096; i += 256) {
        unsigned e = (xw[i] >> 7) & 0xFF;          // bf16 exponent field
        if (e >= 0xC0) f32ev = 1;                  // impossible for real bf16 data
    }
    if (f32ev) atomicOr(&s_f32, 1);
    __syncthreads();
    if (t == 0) { flags[0] = s_odd ? 0 : 1; flags[1] = s_f32; }
}

// ---------------------------------------------------------------- CSR build v2
static __device__ __forceinline__ int dec_src(const unsigned* ew, int E, bool i64, int e) {
    return i64 ? (int)ew[2 * (size_t)e] : (int)ew[e];
}
static __device__ __forceinline__ int dec_dst(const unsigned* ew, int E, bool i64, int e) {
    return i64 ? (int)ew[2 * (size_t)E + 2 * (size_t)e] : (int)ew[(size_t)E + e];
}

__global__ __launch_bounds__(256) void coarse_count(const unsigned* __restrict__ ew, int E,
        const int* __restrict__ flags, int* __restrict__ ccnt) {
    __shared__ int h[512];
    int tid = threadIdx.x;
    for (int i = tid; i < 512; i += 256) h[i] = 0;
    __syncthreads();
    bool i64 = flags[0] != 0;
    int base = blockIdx.x * 8192;
    int lim = min(base + 8192, E);
    for (int e = base + tid; e < lim; e += 256)
        atomicAdd(&h[dec_dst(ew, E, i64, e) >> 8], 1);
    __syncthreads();
    for (int i = tid; i < 512; i += 256) if (h[i]) atomicAdd(&ccnt[i], h[i]);
}

__global__ __launch_bounds__(256) void coarse_scan(const int* __restrict__ ccnt,
        int* __restrict__ cbase, int* __restrict__ ccur, int NBINS) {
    __shared__ int part[256];
    int t = threadIdx.x;
    int v0 = (2 * t     < NBINS) ? ccnt[2 * t]     : 0;
    int v1 = (2 * t + 1 < NBINS) ? ccnt[2 * t + 1] : 0;
    int sum = v0 + v1;
    part[t] = sum;
    __syncthreads();
    for (int off = 1; off < 256; off <<= 1) {
        int u = (t >= off) ? part[t - off] : 0;
        __syncthreads();
        part[t] += u;
        __syncthreads();
    }
    int run = part[t] - sum;
    if (2 * t < NBINS)     { cbase[2 * t] = run;     ccur[2 * t] = run; }
    run += v0;
    if (2 * t + 1 < NBINS) { cbase[2 * t + 1] = run; ccur[2 * t + 1] = run; }
    if (t == 255) cbase[NBINS] = part[255];
}

__global__ __launch_bounds__(256) void coarse_scatter(const unsigned* __restrict__ ew, int E,
        const int* __restrict__ flags, int* __restrict__ ccur,
        uint2* __restrict__ pairs, int NBINS) {
    __shared__ int hist[512];
    __shared__ int hscan[513];
    __shared__ int fbase[512];
    __shared__ int part[256];
    __shared__ uint2 stage[2048];
    int tid = threadIdx.x;
    bool i64 = flags[0] != 0;
    int base = blockIdx.x * 2048;
    int cnt = min(2048, E - base);
    for (int i = tid; i < 512; i += 256) hist[i] = 0;
    __syncthreads();
    int myb[8], myo[8], mys[8], myd[8];
    #pragma unroll
    for (int j = 0; j < 8; ++j) {
        int e = base + j * 256 + tid;
        myb[j] = -1;
        if (e < E) {
            mys[j] = dec_src(ew, E, i64, e);
            int d = dec_dst(ew, E, i64, e);
            myd[j] = d & 255;
            myb[j] = d >> 8;
            myo[j] = atomicAdd(&hist[myb[j]], 1);
        }
    }
    __syncthreads();
    {
        int v0 = hist[2 * tid], v1 = hist[2 * tid + 1];
        int sum = v0 + v1;
        part[tid] = sum;
        __syncthreads();
        for (int off = 1; off < 256; off <<= 1) {
            int u = (tid >= off) ? part[tid - off] : 0;
            __syncthreads();
            part[tid] += u;
            __syncthreads();
        }
        int run = part[tid] - sum;
        hscan[2 * tid] = run;
        hscan[2 * tid + 1] = run + v0;
        if (tid == 255) hscan[512] = part[255];
    }
    __syncthreads();
    #pragma unroll
    for (int j = 0; j < 8; ++j)
        if (myb[j] >= 0) {
            uint2 p; p.x = (unsigned)mys[j]; p.y = (unsigned)myd[j];
            stage[hscan[myb[j]] + myo[j]] = p;
        }
    for (int i = tid; i < NBINS; i += 256) {
        int c = hist[i];
        if (c) fbase[i] = atomicAdd(&ccur[i], c);
    }
    __syncthreads();
    for (int i = tid; i < cnt; i += 256) {
        int lo = 0, hi = NBINS;
        while (hi - lo > 1) {
            int mid = (lo + hi) >> 1;
            if (hscan[mid] <= i) lo = mid; else hi = mid;
        }
        pairs[(size_t)fbase[lo] + (i - hscan[lo])] = stage[i];
    }
}

__global__ __launch_bounds__(256) void bin_degree(const uint2* __restrict__ pairs,
        const int* __restrict__ cbase, int* __restrict__ deg, int N) {
    __shared__ int dl[256];
    int tid = threadIdx.x, b = blockIdx.x;
    dl[tid] = 0;
    __syncthreads();
    int s = cbase[b], e = cbase[b + 1];
    for (int i = s + tid; i < e; i += 256) atomicAdd(&dl[pairs[i].y], 1);
    __syncthreads();
    int node = (b << 8) + tid;
    if (node < N) deg[node] = dl[tid];
}

__global__ __launch_bounds__(256) void bin_scatter(const uint2* __restrict__ pairs,
        const int* __restrict__ cbase, const int* __restrict__ rowptr,
        int* __restrict__ ebuf, int N) {
    __shared__ int cur[256];
    int tid = threadIdx.x, b = blockIdx.x;
    int node = (b << 8) + tid;
    cur[tid] = (node < N) ? rowptr[node] : 0;
    __syncthreads();
    int s = cbase[b], e = cbase[b + 1];
    for (int i = s + tid; i < e; i += 256) {
        uint2 p = pairs[i];
        int pos = atomicAdd(&cur[p.y], 1);
        ebuf[pos] = (int)p.x;
    }
}

// ---- 3-phase multi-block exclusive scan over deg ----
__global__ __launch_bounds__(256) void scan_phaseA(const int* __restrict__ deg,
        int* __restrict__ blocksum, int N) {
    __shared__ int red[256];
    int i0 = blockIdx.x * 512 + threadIdx.x * 2;
    int s = 0;
    if (i0 < N)     s += deg[i0];
    if (i0 + 1 < N) s += deg[i0 + 1];
    red[threadIdx.x] = s;
    __syncthreads();
    for (int off = 128; off; off >>= 1) {
        if (threadIdx.x < off) red[threadIdx.x] += red[threadIdx.x + off];
        __syncthreads();
    }
    if (threadIdx.x == 0) blocksum[blockIdx.x] = red[0];
}

__global__ __launch_bounds__(256) void scan_phaseB(int* __restrict__ blocksum, int NB,
        int* __restrict__ rowptr, int N) {
    __shared__ int part[256];
    int t = threadIdx.x;
    int v[4]; int sum = 0;
    #pragma unroll
    for (int j = 0; j < 4; ++j) {
        int i = 4 * t + j;
        v[j] = (i < NB) ? blocksum[i] : 0;
        sum += v[j];
    }
    part[t] = sum;
    __syncthreads();
    for (int off = 1; off < 256; off <<= 1) {
        int u = (t >= off) ? part[t - off] : 0;
        __syncthreads();
        part[t] += u;
        __syncthreads();
    }
    int run = part[t] - sum;
    #pragma unroll
    for (int j = 0; j < 4; ++j) {
        int i = 4 * t + j;
        if (i < NB) blocksum[i] = run;
        run += v[j];
    }
    if (t == 255) rowptr[N] = part[255];
}

__global__ __launch_bounds__(256) void scan_phaseC(const int* __restrict__ deg,
        const int* __restrict__ blockoff, int* __restrict__ rowptr, int N) {
    __shared__ int part[256];
    int t = threadIdx.x;
    int i0 = blockIdx.x * 512 + 2 * t;
    int d0 = (i0 < N)     ? deg[i0]     : 0;
    int d1 = (i0 + 1 < N) ? deg[i0 + 1] : 0;
    int sum = d0 + d1;
    part[t] = sum;
    __syncthreads();
    for (int off = 1; off < 256; off <<= 1) {
        int u = (t >= off) ? part[t - off] : 0;
        __syncthreads();
        part[t] += u;
        __syncthreads();
    }
    int run = blockoff[blockIdx.x] + part[t] - sum;
    if (i0 < N)     rowptr[i0] = run;
    run += d0;
    if (i0 + 1 < N) rowptr[i0 + 1] = run;
}

// ------------------------------------------------------- weight pre-transpose
__global__ void transpose_kernel(const void* __restrict__ W,
        __hip_bfloat16* __restrict__ Wt, int rows, int cols, int ldt,
        const int* __restrict__ flags) {
    int idx = blockIdx.x * blockDim.x + threadIdx.x;
    if (idx < rows * cols) {
        int fi = idx / cols, fo = idx % cols;
        Wt[fo * ldt + fi] = __float2bfloat16(loadf(W, idx, flags[1] != 0));
    }
}

// --------------------------------------------------------------- MFMA GEMM v6
// Block = 128 nodes as 4 waves x TWO 16-node stripes each (256 threads).
// One ds_read of a W-fragment feeds TWO MFMAs. Swizzled W layout (R9).
template<int KSTEPS>
__global__ __launch_bounds__(256) void gemm_v6(
        const void* __restrict__ X0, const void* __restrict__ X1, int K0, int xflag,
        const __hip_bfloat16* __restrict__ Wt, const void* __restrict__ bias,
        void* __restrict__ outp, int ldo, int out_f32, int M, int Ncols,
        const int* __restrict__ flags) {
    constexpr int K = KSTEPS * 32;
    constexpr int CH = K / 8;              // 16B chunks per W row
    constexpr int SITERS = (64 * CH) / 256;
    __shared__ short Wf[4 * KSTEPS * 64 * 8];   // 32KB @ K=256
    bool pf = flags[1] != 0;
    bool xf32 = (xflag != 0) && pf;
    int tid = threadIdx.x;
    int wave = tid >> 6, lane = tid & 63;
    int quad = lane >> 4, r = lane & 15;
    int nodeA = blockIdx.x * 128 + wave * 32 + r;
    int nodeB = nodeA + 16;
    int nA = min(nodeA, M - 1);
    int nB = min(nodeB, M - 1);

    bf16x8 xfA[KSTEPS], xfB[KSTEPS];
    if (xf32) {
        #pragma unroll
        for (int ks = 0; ks < KSTEPS; ++ks) {
            int k = ks * 32 + quad * 8;
            const float* pA = (k < K0)
                ? ((const float*)X0 + (size_t)nA * K0 + k)
                : ((const float*)X1 + (size_t)nA * (K - K0) + (k - K0));
            const float* pB = (k < K0)
                ? ((const float*)X0 + (size_t)nB * K0 + k)
                : ((const float*)X1 + (size_t)nB * (K - K0) + (k - K0));
            float4 a0 = *(const float4*)pA;
            float4 a1 = *(const float4*)(pA + 4);
            float4 b0 = *(const float4*)pB;
            float4 b1 = *(const float4*)(pB + 4);
            bf16x8 ta, tb;
            ta[0] = f2bs(a0.x); ta[1] = f2bs(a0.y); ta[2] = f2bs(a0.z); ta[3] = f2bs(a0.w);
            ta[4] = f2bs(a1.x); ta[5] = f2bs(a1.y); ta[6] = f2bs(a1.z); ta[7] = f2bs(a1.w);
            tb[0] = f2bs(b0.x); tb[1] = f2bs(b0.y); tb[2] = f2bs(b0.z); tb[3] = f2bs(b0.w);
            tb[4] = f2bs(b1.x); tb[5] = f2bs(b1.y); tb[6] = f2bs(b1.z); tb[7] = f2bs(b1.w);
            xfA[ks] = ta;
            xfB[ks] = tb;
        }
    } else {
        #pragma unroll
        for (int ks = 0; ks < KSTEPS; ++ks) {
            int k = ks * 32 + quad * 8;
            const __hip_bfloat16* pA = (k < K0)
                ? ((const __hip_bfloat16*)X0 + (size_t)nA * K0 + k)
                : ((const __hip_bfloat16*)X1 + (size_t)nA * (K - K0) + (k - K0));
            const __hip_bfloat16* pB = (k < K0)
                ? ((const __hip_bfloat16*)X0 + (size_t)nB * K0 + k)
                : ((const __hip_bfloat16*)X1 + (size_t)nB * (K - K0) + (k - K0));
            xfA[ks] = *(const bf16x8*)pA;
            xfB[ks] = *(const bf16x8*)pB;
        }
    }

    int nphases = Ncols >> 6;              // 64 cols per phase
    for (int p = 0; p < nphases; ++p) {
        if (p) __syncthreads();
        #pragma unroll
        for (int i = 0; i < SITERS; ++i) {
            int idx = i * 256 + tid;
            int row_l = idx / CH, c = idx % CH;
            uint4 v = *(const uint4*)((const short*)Wt + (size_t)(p * 64 + row_l) * K + c * 8);
            int ftl = row_l >> 4, rr = row_l & 15;
            int ks = c >> 2, q = c & 3;
            int chunk = ((q * 16 + rr) ^ ks);       // XOR swizzle
            *(uint4*)(Wf + (size_t)(((ftl * KSTEPS + ks) * 64) + chunk) * 8) = v;
        }
        __syncthreads();
        #pragma unroll
        for (int ftl = 0; ftl < 4; ++ftl) {
            f32x4 accA = {0.f, 0.f, 0.f, 0.f};
            f32x4 accB = {0.f, 0.f, 0.f, 0.f};
            #pragma unroll
            for (int ks = 0; ks < KSTEPS; ++ks) {
                bf16x8 wf = *(const bf16x8*)(Wf + (size_t)((ftl * KSTEPS + ks) * 64 + (lane ^ ks)) * 8);
                accA = __builtin_amdgcn_mfma_f32_16x16x32_bf16(wf, xfA[ks], accA, 0, 0, 0);
                accB = __builtin_amdgcn_mfma_f32_16x16x32_bf16(wf, xfB[ks], accB, 0, 0, 0);
            }
            int fo = p * 64 + ftl * 16 + quad * 4;
            float b0 = 0.f, b1 = 0.f, b2 = 0.f, b3 = 0.f;
            if (bias) {
                b0 = loadf(bias, fo + 0, pf); b1 = loadf(bias, fo + 1, pf);
                b2 = loadf(bias, fo + 2, pf); b3 = loadf(bias, fo + 3, pf);
            }
            if (out_f32) {
                if (nodeA < M) {
                    float4 res;
                    res.x = accA[0] + b0; res.y = accA[1] + b1;
                    res.z = accA[2] + b2; res.w = accA[3] + b3;
                    *(float4*)((float*)outp + (size_t)nodeA * ldo + fo) = res;
                }
                if (nodeB < M) {
                    float4 res;
                    res.x = accB[0] + b0; res.y = accB[1] + b1;
                    res.z = accB[2] + b2; res.w = accB[3] + b3;
                    *(float4*)((float*)outp + (size_t)nodeB * ldo + fo) = res;
                }
            } else {
                if (nodeA < M) {
                    short4 res;
                    res.x = f2bs(accA[0] + b0); res.y = f2bs(accA[1] + b1);
                    res.z = f2bs(accA[2] + b2); res.w = f2bs(accA[3] + b3);
                    *(short4*)((short*)outp + (size_t)nodeA * ldo + fo) = res;
                }
                if (nodeB < M) {
                    short4 res;
                    res.x = f2bs(accB[0] + b0); res.y = f2bs(accB[1] + b1);
                    res.z = f2bs(accB[2] + b2); res.w = f2bs(accB[3] + b3);
                    *(short4*)((short*)outp + (size_t)nodeB * ldo + fo) = res;
                }
            }
        }
    }
}

// --------------------------------------- fused mean-agg + bias + lin_r + LN + ReLU
__global__ __launch_bounds__(256) void agg_ln_relu(
        const __hip_bfloat16* __restrict__ yz, const int* __restrict__ rowptr,
        const int* __restrict__ ebuf,
        const void* __restrict__ bn, const void* __restrict__ g,
        const void* __restrict__ be, __hip_bfloat16* __restrict__ hout, int N,
        const int* __restrict__ flags) {
    int node = (blockIdx.x * blockDim.x + threadIdx.x) >> 6;
    if (node >= N) return;
    node = __builtin_amdgcn_readfirstlane(node);
    bool pf = flags[1] != 0;
    int lane = threadIdx.x & 63;
    int f = lane * 2;
    const short* yzs = (const short*)yz;
    int start = rowptr[node], end = rowptr[node + 1];
    float a0 = 0.f, a1 = 0.f;
    int i = start;
    for (; i + 8 <= end; i += 8) {
        int n0 = ebuf[i + 0], n1 = ebuf[i + 1], n2 = ebuf[i + 2], n3 = ebuf[i + 3];
        int n4 = ebuf[i + 4], n5 = ebuf[i + 5], n6 = ebuf[i + 6], n7 = ebuf[i + 7];
        short2 t0 = *(const short2*)(yzs + (size_t)n0 * 256 + f);
        short2 t1 = *(const short2*)(yzs + (size_t)n1 * 256 + f);
        short2 t2 = *(const short2*)(yzs + (size_t)n2 * 256 + f);
        short2 t3 = *(const short2*)(yzs + (size_t)n3 * 256 + f);
        short2 t4 = *(const short2*)(yzs + (size_t)n4 * 256 + f);
        short2 t5 = *(const short2*)(yzs + (size_t)n5 * 256 + f);
        short2 t6 = *(const short2*)(yzs + (size_t)n6 * 256 + f);
        short2 t7 = *(const short2*)(yzs + (size_t)n7 * 256 + f);
        a0 += bs2f(t0.x) + bs2f(t1.x) + bs2f(t2.x) + bs2f(t3.x)
            + bs2f(t4.x) + bs2f(t5.x) + bs2f(t6.x) + bs2f(t7.x);
        a1 += bs2f(t0.y) + bs2f(t1.y) + bs2f(t2.y) + bs2f(t3.y)
            + bs2f(t4.y) + bs2f(t5.y) + bs2f(t6.y) + bs2f(t7.y);
    }
    for (; i + 2 <= end; i += 2) {
        int n0 = ebuf[i + 0], n1 = ebuf[i + 1];
        short2 t0 = *(const short2*)(yzs + (size_t)n0 * 256 + f);
        short2 t1 = *(const short2*)(yzs + (size_t)n1 * 256 + f);
        a0 += bs2f(t0.x) + bs2f(t1.x);
        a1 += bs2f(t0.y) + bs2f(t1.y);
    }
    if (i < end) {
        int n0 = ebuf[i];
        short2 t0 = *(const short2*)(yzs + (size_t)n0 * 256 + f);
        a0 += bs2f(t0.x);
        a1 += bs2f(t0.y);
    }
    float inv = 1.f / fmaxf((float)(end - start), 1.f);
    short2 zt = *(const short2*)(yzs + (size_t)node * 256 + 128 + f);
    float v0 = a0 * inv + loadf(bn, f, pf)     + bs2f(zt.x);
    float v1 = a1 * inv + loadf(bn, f + 1, pf) + bs2f(zt.y);
    float s = v0 + v1;
    #pragma unroll
    for (int off = 32; off > 0; off >>= 1) s += __shfl_xor(s, off, 64);
    float mu = s * (1.f / 128.f);
    float d0 = v0 - mu, d1 = v1 - mu;
    float q = d0 * d0 + d1 * d1;
    #pragma unroll
    for (int off = 32; off > 0; off >>= 1) q += __shfl_xor(q, off, 64);
    float rstd = rsqrtf(q * (1.f / 128.f) + 1e-5f);
    float o0 = fmaxf(d0 * rstd * loadf(g, f, pf)     + loadf(be, f, pf),     0.f);
    float o1 = fmaxf(d1 * rstd * loadf(g, f + 1, pf) + loadf(be, f + 1, pf), 0.f);
    short* hp = (short*)hout + (size_t)node * 128 + f;
    hp[0] = f2bs(o0);
    hp[1] = f2bs(o1);
}

// ------------------------------------------------------------- MLP head v2 (MFMA)
// out = relu(feats@Wh1+bh1)@Wh2+bh2, feats f32 [N][128].
// Block = 128 nodes (4 waves x 2 stripes). Stage 1: Wth1 (=Wh1^T, 32x128 bf16)
// staged swizzled in LDS once per 128 nodes (R10's head re-read Wh1 from L1
// 12500x and ran 128-long serial FMA chains: VALU 28%, Mfma 0, 75us).
// Hidden round-trips LDS (f32, stride 34) to convert D-layout -> row-major.
// Stage 2 (K=32, 16 cols) on VALU, 8 independent accs, Wh2 via L1 broadcast.
__global__ __launch_bounds__(256) void head_v2(
        const float* __restrict__ feats, const __hip_bfloat16* __restrict__ Wth1,
        const void* __restrict__ bh1, const void* __restrict__ Wh2,
        const void* __restrict__ bh2, void* __restrict__ outp, int N,
        const int* __restrict__ flags) {
    constexpr int KSTEPS = 4;              // K = 128
    constexpr int CH = 16;                 // 16B chunks per W row
    constexpr int HS = 34;                 // hid LDS stride (f32) — breaks 32-stride banks
    __shared__ short Wf[2 * KSTEPS * 64 * 8];   // 8 KB
    __shared__ float hid[128 * HS];             // 17 KB
    bool pf = flags[1] != 0;
    int tid = threadIdx.x;
    int wave = tid >> 6, lane = tid & 63;
    int quad = lane >> 4, r = lane & 15;
    int nodeA = blockIdx.x * 128 + wave * 32 + r;
    int nodeB = nodeA + 16;
    int nA = min(nodeA, N - 1);
    int nB = min(nodeB, N - 1);

    // X fragments from feats (always f32)
    bf16x8 xfA[KSTEPS], xfB[KSTEPS];
    #pragma unroll
    for (int ks = 0; ks < KSTEPS; ++ks) {
        int k = ks * 32 + quad * 8;
        const float* pA = feats + (size_t)nA * 128 + k;
        const float* pB = feats + (size_t)nB * 128 + k;
        float4 a0 = *(const float4*)pA;
        float4 a1 = *(const float4*)(pA + 4);
        float4 b0 = *(const float4*)pB;
        float4 b1 = *(const float4*)(pB + 4);
        bf16x8 ta, tb;
        ta[0] = f2bs(a0.x); ta[1] = f2bs(a0.y); ta[2] = f2bs(a0.z); ta[3] = f2bs(a0.w);
        ta[4] = f2bs(a1.x); ta[5] = f2bs(a1.y); ta[6] = f2bs(a1.z); ta[7] = f2bs(a1.w);
        tb[0] = f2bs(b0.x); tb[1] = f2bs(b0.y); tb[2] = f2bs(b0.z); tb[3] = f2bs(b0.w);
        tb[4] = f2bs(b1.x); tb[5] = f2bs(b1.y); tb[6] = f2bs(b1.z); tb[7] = f2bs(b1.w);
        xfA[ks] = ta;
        xfB[ks] = tb;
    }

    // stage Wth1 (32 rows x 128) swizzled: 32*CH = 512 chunks, 2 iters
    #pragma unroll
    for (int i = 0; i < 2; ++i) {
        int idx = i * 256 + tid;
        int row_l = idx / CH, c = idx % CH;
        uint4 v = *(const uint4*)((const short*)Wth1 + (size_t)row_l * 128 + c * 8);
        int ftl = row_l >> 4, rr = row_l & 15;
        int ks = c >> 2, q = c & 3;
        int chunk = ((q * 16 + rr) ^ ks);
        *(uint4*)(Wf + (size_t)(((ftl * KSTEPS + ks) * 64) + chunk) * 8) = v;
    }
    __syncthreads();

    // stage 1 MFMA: hidden = relu(feats@Wh1 + bh1), write to hid LDS
    #pragma unroll
    for (int ftl = 0; ftl < 2; ++ftl) {
        f32x4 accA = {0.f, 0.f, 0.f, 0.f};
        f32x4 accB = {0.f, 0.f, 0.f, 0.f};
        #pragma unroll
        for (int ks = 0; ks < KSTEPS; ++ks) {
            bf16x8 wf = *(const bf16x8*)(Wf + (size_t)((ftl * KSTEPS + ks) * 64 + (lane ^ ks)) * 8);
            accA = __builtin_amdgcn_mfma_f32_16x16x32_bf16(wf, xfA[ks], accA, 0, 0, 0);
            accB = __builtin_amdgcn_mfma_f32_16x16x32_bf16(wf, xfB[ks], accB, 0, 0, 0);
        }
        int fo = ftl * 16 + quad * 4;
        float b0 = loadf(bh1, fo + 0, pf), b1 = loadf(bh1, fo + 1, pf);
        float b2 = loadf(bh1, fo + 2, pf), b3 = loadf(bh1, fo + 3, pf);
        float* hA = hid + (size_t)(wave * 32 + r) * HS + fo;
        hA[0] = fmaxf(accA[0] + b0, 0.f); hA[1] = fmaxf(accA[1] + b1, 0.f);
        hA[2] = fmaxf(accA[2] + b2, 0.f); hA[3] = fmaxf(accA[3] + b3, 0.f);
        float* hB = hid + (size_t)(wave * 32 + 16 + r) * HS + fo;
        hB[0] = fmaxf(accB[0] + b0, 0.f); hB[1] = fmaxf(accB[1] + b1, 0.f);
        hB[2] = fmaxf(accB[2] + b2, 0.f); hB[3] = fmaxf(accB[3] + b3, 0.f);
    }
    __syncthreads();

    // stage 2 (VALU): lane -> node = wave*32 + (lane&31), cols cg*8..cg*8+7
    int li = lane & 31, cg = lane >> 5;
    int node = blockIdx.x * 128 + wave * 32 + li;
    const float* hrow = hid + (size_t)(wave * 32 + li) * HS;
    float acc[8];
    #pragma unroll
    for (int i = 0; i < 8; ++i) acc[i] = loadf(bh2, cg * 8 + i, pf);
    #pragma unroll 4
    for (int k = 0; k < 32; ++k) {
        float hv = hrow[k];
        #pragma unroll
        for (int i = 0; i < 8; ++i)
            acc[i] += hv * loadf(Wh2, k * 16 + cg * 8 + i, pf);
    }
    if (node < N) {
        if (pf) {
            float* op = (float*)outp + (size_t)node * 16 + cg * 8;
            float4 r0 = {acc[0], acc[1], acc[2], acc[3]};
            float4 r1 = {acc[4], acc[5], acc[6], acc[7]};
            *(float4*)op = r0;
            *(float4*)(op + 4) = r1;
        } else {
            short* op = (short*)outp + (size_t)node * 16 + cg * 8;
            short4 r0, r1;
            r0.x = f2bs(acc[0]); r0.y = f2bs(acc[1]); r0.z = f2bs(acc[2]); r0.w = f2bs(acc[3]);
            r1.x = f2bs(acc[4]); r1.y = f2bs(acc[5]); r1.z = f2bs(acc[6]); r1.w = f2bs(acc[7]);
            *(short4*)op = r0;
            *(short4*)(op + 4) = r1;
        }
    }
}

// ---------------------------------------------------------------- launcher
extern "C" void kernel_launch(void* const* d_in, const int* in_sizes, int n_in,
                              void* d_out, int out_size, void* d_ws, size_t ws_size,
                              hipStream_t stream) {
    const void* x    = d_in[0];
    const unsigned* ei = (const unsigned*)d_in[1];
    const void* Wnl0 = d_in[2];
    const void* bnl0 = d_in[3];
    const void* Wr0  = d_in[4];
    const void* Wnl1 = d_in[5];
    const void* bnl1 = d_in[6];
    const void* Wr1  = d_in[7];
    const void* g0   = d_in[8];
    const void* be0  = d_in[9];
    const void* g1   = d_in[10];
    const void* be1  = d_in[11];
    const void* Wjk  = d_in[12];
    const void* bjk  = d_in[13];
    const void* Wh1  = d_in[14];
    const void* bh1  = d_in[15];
    const void* Wh2  = d_in[16];
    const void* bh2  = d_in[17];

    const int N = in_sizes[0] / 256;
    const int E = in_sizes[1] / 2;
    const int NBINS = (N + 255) >> 8;

    char* ws = (char*)d_ws;
    size_t off = 0;
    auto alloc = [&](size_t bytes) -> void* {
        void* p = ws + off;
        off = (off + bytes + 255) & ~(size_t)255;
        return p;
    };
    int* flags  = (int*)alloc(256);
    int* rowptr = (int*)alloc((size_t)(N + 1) * 4);
    int* deg    = (int*)alloc((size_t)N * 4);
    int* ebuf   = (int*)alloc((size_t)E * 4);
    int* blocksum = (int*)alloc(1024 * 4);
    int* ccnt   = (int*)alloc(512 * 4);
    int* cbase  = (int*)alloc(513 * 4);
    int* ccur   = (int*)alloc(512 * 4);
    uint2* pairs = (uint2*)alloc((size_t)E * 8);
    __hip_bfloat16* Wt0  = (__hip_bfloat16*)alloc(256 * 256 * 2);
    __hip_bfloat16* Wt1  = (__hip_bfloat16*)alloc(256 * 128 * 2);
    __hip_bfloat16* Wtjk = (__hip_bfloat16*)alloc(128 * 256 * 2);
    __hip_bfloat16* Wth1 = (__hip_bfloat16*)alloc(32 * 128 * 2);
    __hip_bfloat16* yz = (__hip_bfloat16*)alloc((size_t)N * 256 * 2);
    __hip_bfloat16* h0 = (__hip_bfloat16*)alloc((size_t)N * 128 * 2);
    __hip_bfloat16* h1 = (__hip_bfloat16*)alloc((size_t)N * 128 * 2);
    float* feats = (float*)yz;   // yz dead after second agg; same byte size

    // dtype detection
    detect_kernel<<<1, 256, 0, stream>>>(ei, (const unsigned short*)x, flags);

    // CSR build v2 (two-level binned counting sort)
    (void)hipMemsetAsync(ccnt, 0, 512 * 4, stream);
    coarse_count<<<(E + 8191) / 8192, 256, 0, stream>>>(ei, E, flags, ccnt);
    coarse_scan<<<1, 256, 0, stream>>>(ccnt, cbase, ccur, NBINS);
    coarse_scatter<<<(E + 2047) / 2048, 256, 0, stream>>>(ei, E, flags, ccur, pairs, NBINS);
    bin_degree<<<NBINS, 256, 0, stream>>>(pairs, cbase, deg, N);
    int NB = (N + 511) / 512;
    scan_phaseA<<<NB, 256, 0, stream>>>(deg, blocksum, N);
    scan_phaseB<<<1, 256, 0, stream>>>(blocksum, NB, rowptr, N);
    scan_phaseC<<<NB, 256, 0, stream>>>(deg, blocksum, rowptr, N);
    bin_scatter<<<NBINS, 256, 0, stream>>>(pairs, cbase, rowptr, ebuf, N);

    // Weight transposes
    transpose_kernel<<<(256 * 128 + 255) / 256, 256, 0, stream>>>(Wnl0, Wt0, 256, 128, 256, flags);
    transpose_kernel<<<(256 * 128 + 255) / 256, 256, 0, stream>>>(Wr0,  Wt0 + 128 * 256, 256, 128, 256, flags);
    transpose_kernel<<<(128 * 128 + 255) / 256, 256, 0, stream>>>(Wnl1, Wt1, 128, 128, 128, flags);
    transpose_kernel<<<(128 * 128 + 255) / 256, 256, 0, stream>>>(Wr1,  Wt1 + 128 * 128, 128, 128, 128, flags);
    transpose_kernel<<<(256 * 128 + 255) / 256, 256, 0, stream>>>(Wjk,  Wtjk, 256, 128, 256, flags);
    transpose_kernel<<<(128 * 32 + 255) / 256, 256, 0, stream>>>(Wh1,  Wth1, 128, 32, 128, flags);

    int gblocks = (N + 127) / 128;    // 128 nodes per block (4 waves x 2 stripes)
    int ablocks = (int)(((size_t)N * 64 + 255) / 256);

    // layer 0: project (y0 = x@Wnl0, z0 = x@Wr0) -> agg+LN+ReLU -> h0
    gemm_v6<8><<<gblocks, 256, 0, stream>>>(x, x, 256, 1, Wt0, nullptr, yz, 256, 0, N, 256, flags);
    agg_ln_relu<<<ablocks, 256, 0, stream>>>(yz, rowptr, ebuf, bnl0, g0, be0, h0, N, flags);

    // layer 1 (K=128)
    gemm_v6<4><<<gblocks, 256, 0, stream>>>(h0, h0, 128, 0, Wt1, nullptr, yz, 256, 0, N, 256, flags);
    agg_ln_relu<<<ablocks, 256, 0, stream>>>(yz, rowptr, ebuf, bnl1, g1, be1, h1, N, flags);

    // JK: feats = [h0|h1] @ Wjk + bjk   (K split 128/128), f32 output
    gemm_v6<8><<<gblocks, 256, 0, stream>>>(h0, h1, 128, 0, Wtjk, bjk, feats, 128, 1, N, 128, flags);

    // MLP head (MFMA stage 1 + VALU stage 2)
    head_v2<<<gblocks, 256, 0, stream>>>(feats, Wth1, bh1, Wh2, bh2, d_out, N, flags);
}